// Round 1
// baseline (149.590 us; speedup 1.0000x reference)
//
#include <hip/hip_runtime.h>

#define NTHREADS 256

// (LAT_SHAPE+1) * (LON_SHAPE+1) = 721 * 1441
constexpr int TABLE_SZ = 721 * 1441;

__global__ __launch_bounds__(NTHREADS)
void ngp_interp_kernel(const float* __restrict__ x,
                       const float* __restrict__ emb,
                       float* __restrict__ out,
                       int B)
{
    int p = blockIdx.x * NTHREADS + threadIdx.x;
    if (p >= B) return;

    const float2 xp = *reinterpret_cast<const float2*>(x + (size_t)p * 2);
    const float xlat = xp.x;
    const float xlon = xp.y;

    // box = [LAT_MIN - FINEST, LON_MIN - FINEST] .. [LAT_MAX + FINEST, LON_MAX + FINEST]
    const float bmin_lat = -90.25f, bmax_lat = 90.25f;
    const float bmin_lon = -0.25f,  bmax_lon = 360.25f;
    const float xc_lat = fminf(fmaxf(xlat, bmin_lat), bmax_lat);
    const float xc_lon = fminf(fmaxf(xlon, bmin_lon), bmax_lon);

    const float r = 0.017453292519943295f;   // pi/180 in fp32
    // s2_tab[i] = sin(gs_i * r / 2), gs = 1,2,4,8  (denominator half-angle sine)
    const float s2_tab[4] = {0.008726535498f, 0.017452406437f,
                             0.034899496703f, 0.069756473744f};

    float o[8];

    #pragma unroll
    for (int i = 0; i < 4; ++i) {
        const float gs     = (float)(1 << i);
        const float inv_gs = 1.0f / gs;       // gs is a power of 2: mul == div exactly
        const int   width  = 1440 >> i;

        // bl must be bit-identical to np: fp32 sub, exact pow2 div, floor
        const float blat_f = floorf((xc_lat - bmin_lat) * inv_gs);
        const float blon_f = floorf((xc_lon - bmin_lon) * inv_gs);
        const float gmin_lat = blat_f * gs + bmin_lat;
        const float gmin_lon = blon_f * gs + bmin_lon;
        const float gmax_lon = gmin_lon + gs;

        const int idx00 = (int)blat_f * width + (int)blon_f;
        const float* base0 = emb + ((size_t)i * TABLE_SZ + (size_t)idx00) * 2;
        const float* base1 = base0 + (size_t)width * 2;
        // corners: e0=(0,0) e1=(0,+1) e2=(+1,0) e3=(+1,+1); feature pairs contiguous
        const float2 e0 = *reinterpret_cast<const float2*>(base0);
        const float2 e1 = *reinterpret_cast<const float2*>(base0 + 2);
        const float2 e2 = *reinterpret_cast<const float2*>(base1);
        const float2 e3 = *reinterpret_cast<const float2*>(base1 + 2);

        // wlat: meridian geodesic ratio == (x_lat - gmin_lat) / gs
        const float wlat = (xlat - gmin_lat) * inv_gs;

        // wlon: geodesic along parallel at gmin_lat, measured x -> gmax (per reference!)
        // dist = 2*asin(|cos(lat)| * sin(dlon/2)); ratio num/den
        const float ca = fabsf(__cosf(gmin_lat * r));
        const float h1 = (gmax_lon - xlon) * r * 0.5f;            // <= 0.0699 rad
        const float s1 = h1 - h1 * h1 * h1 * (1.0f / 6.0f);       // sin(h1), rel err ~2e-7
        const float z1 = ca * s1;
        const float z2 = ca * s2_tab[i];
        const float n1 = z1 + z1 * z1 * z1 * (1.0f / 6.0f);       // asin(z1), rel err ~2e-6
        const float n2 = z2 + z2 * z2 * z2 * (1.0f / 6.0f);       // asin(z2)
        const float wlon = n1 * __builtin_amdgcn_rcpf(n2);

        const float c0x = e0.x + (e2.x - e0.x) * wlat;
        const float c0y = e0.y + (e2.y - e0.y) * wlat;
        const float c1x = e1.x + (e3.x - e1.x) * wlat;
        const float c1y = e1.y + (e3.y - e1.y) * wlat;
        o[2*i]   = c0x + (c1x - c0x) * wlon;
        o[2*i+1] = c0y + (c1y - c0y) * wlon;
    }

    float4* op = reinterpret_cast<float4*>(out + (size_t)p * 8);
    op[0] = make_float4(o[0], o[1], o[2], o[3]);
    op[1] = make_float4(o[4], o[5], o[6], o[7]);
}

extern "C" void kernel_launch(void* const* d_in, const int* in_sizes, int n_in,
                              void* d_out, int out_size, void* d_ws, size_t ws_size,
                              hipStream_t stream)
{
    const float* x   = (const float*)d_in[0];   // (B, 2) fp32
    const float* emb = (const float*)d_in[1];   // (4, TABLE, 2) fp32
    float* out = (float*)d_out;                 // (B, 8) fp32
    const int B = in_sizes[0] / 2;
    const int grid = (B + NTHREADS - 1) / NTHREADS;
    ngp_interp_kernel<<<grid, NTHREADS, 0, stream>>>(x, emb, out, B);
}